// Round 1
// baseline (5776.291 us; speedup 1.0000x reference)
//
#include <hip/hip_runtime.h>
#include <math.h>

// ResBlock: op2 = conv3x3(x, w2); a = concat(prelu(op2[0::3]), relu(op2[1::3]), tanh(op2[2::3]));
//           out = conv3x3(a, w3) * 0.1 + x
// B=16, C=256, H=W=96, fp32.

#define Bn 16
#define Cn 256
#define Hn 96
#define Wn 96
#define HW (Hn*Wn)
#define TH 16        // spatial tile rows per block
#define TW 32        // spatial tile cols per block
#define CO_T 32      // output channels per block
#define CI_B 8       // input-channel chunk staged in LDS
#define LROWS (TH+2)
#define LCOLS (TW+2)
#define LSTRIDE 36   // padded LDS row stride (floats), 144B = 16B-aligned

// Transpose weights [co][ci][kh][kw] -> [ci][k][co] so the conv kernel's
// LDS weight loads are coalesced along co.
__global__ __launch_bounds__(256)
void transpose_w_k(const float* __restrict__ w, float* __restrict__ wT) {
    int idx = blockIdx.x * 256 + threadIdx.x;
    if (idx >= Cn * Cn * 9) return;
    int k  = idx % 9;
    int ci = (idx / 9) % Cn;
    int co = idx / (9 * Cn);
    wT[(ci * 9 + k) * Cn + co] = w[idx];
}

// MODE 0: in = x, out = a (activation + channel permutation fused)
// MODE 1: in = a, out = conv*0.1 + xres
template<int MODE>
__global__ __launch_bounds__(256, 2)
void conv3x3_k(const float* __restrict__ in,
               const float* __restrict__ wT,
               const float* __restrict__ prelu_w,
               const float* __restrict__ xres,
               float* __restrict__ out)
{
    __shared__ __align__(16) float s_in[CI_B][LROWS][LSTRIDE];
    __shared__ __align__(16) float s_w[CI_B][9][CO_T];

    const int tid = threadIdx.x;
    const int c0 = (blockIdx.x % 3) * TW;
    const int r0 = (blockIdx.x / 3) * TH;
    const int co_base = blockIdx.y * CO_T;
    const int b = blockIdx.z;

    // 4 co-groups of 8 channels; 8x8 thread grid over the spatial tile,
    // each thread owns 2 rows x 4 cols.
    const int co_off = (tid >> 6) * 8;   // wave-uniform
    const int t64 = tid & 63;
    const int ty = t64 >> 3;             // rows ty*2, ty*2+1
    const int tx = t64 & 7;              // cols tx*4 .. tx*4+3

    float acc[8][8];
    #pragma unroll
    for (int i = 0; i < 8; ++i)
        #pragma unroll
        for (int j = 0; j < 8; ++j) acc[i][j] = 0.f;

    const float* in_b = in + (size_t)b * Cn * HW;

    for (int ci0 = 0; ci0 < Cn; ci0 += CI_B) {
        // ---- stage input tile (with halo, zero-padded at image edges) ----
        for (int idx = tid; idx < CI_B * LROWS * LCOLS; idx += 256) {
            int ci  = idx / (LROWS * LCOLS);
            int rem = idx - ci * (LROWS * LCOLS);
            int r   = rem / LCOLS;
            int c   = rem - r * LCOLS;
            int gr = r0 + r - 1;
            int gc = c0 + c - 1;
            float v = 0.f;
            if ((unsigned)gr < (unsigned)Hn && (unsigned)gc < (unsigned)Wn)
                v = in_b[(size_t)(ci0 + ci) * HW + gr * Wn + gc];
            s_in[ci][r][c] = v;
        }
        // ---- stage weights [ci][k][co] (coalesced along co) ----
        for (int idx = tid; idx < CI_B * 9 * CO_T; idx += 256) {
            int ci  = idx / (9 * CO_T);
            int rem = idx - ci * (9 * CO_T);
            int k   = rem / CO_T;
            int co  = rem - k * CO_T;
            s_w[ci][k][co] = wT[((size_t)(ci0 + ci) * 9 + k) * Cn + co_base + co];
        }
        __syncthreads();

        #pragma unroll
        for (int ci = 0; ci < CI_B; ++ci) {
            // 4 rows x 8 cols of input into registers (16B-aligned b128 reads)
            float rin[4][8];
            #pragma unroll
            for (int rr = 0; rr < 4; ++rr) {
                const float4 v0 = *(const float4*)&s_in[ci][ty * 2 + rr][tx * 4];
                const float4 v1 = *(const float4*)&s_in[ci][ty * 2 + rr][tx * 4 + 4];
                rin[rr][0] = v0.x; rin[rr][1] = v0.y; rin[rr][2] = v0.z; rin[rr][3] = v0.w;
                rin[rr][4] = v1.x; rin[rr][5] = v1.y; rin[rr][6] = v1.z; rin[rr][7] = v1.w;
            }
            #pragma unroll
            for (int kh = 0; kh < 3; ++kh)
            #pragma unroll
            for (int kw = 0; kw < 3; ++kw) {
                // wave-uniform address -> LDS broadcast, conflict-free
                const float4 w0 = *(const float4*)&s_w[ci][kh * 3 + kw][co_off];
                const float4 w1 = *(const float4*)&s_w[ci][kh * 3 + kw][co_off + 4];
                const float wv[8] = {w0.x, w0.y, w0.z, w0.w, w1.x, w1.y, w1.z, w1.w};
                #pragma unroll
                for (int i = 0; i < 8; ++i)
                #pragma unroll
                for (int rr = 0; rr < 2; ++rr)
                #pragma unroll
                for (int cc = 0; cc < 4; ++cc)
                    acc[i][rr * 4 + cc] = fmaf(wv[i], rin[rr + kh][cc + kw], acc[i][rr * 4 + cc]);
            }
        }
        __syncthreads();
    }

    const int orow = r0 + ty * 2;
    const int ocol = c0 + tx * 4;

    if constexpr (MODE == 0) {
        const float pw = prelu_w[0];
        #pragma unroll
        for (int i = 0; i < 8; ++i) {
            const int co = co_base + co_off + i;
            const int q = co / 3;
            const int m = co - 3 * q;  // wave-uniform -> no divergence
            const int dst = (m == 0) ? q : ((m == 1) ? 86 + q : 171 + q);
            float* op = out + ((size_t)b * Cn + dst) * HW + (size_t)orow * Wn + ocol;
            #pragma unroll
            for (int rr = 0; rr < 2; ++rr) {
                const float s0 = acc[i][rr * 4 + 0], s1 = acc[i][rr * 4 + 1];
                const float s2 = acc[i][rr * 4 + 2], s3 = acc[i][rr * 4 + 3];
                float4 v;
                if (m == 0) {
                    v.x = s0 >= 0.f ? s0 : pw * s0;
                    v.y = s1 >= 0.f ? s1 : pw * s1;
                    v.z = s2 >= 0.f ? s2 : pw * s2;
                    v.w = s3 >= 0.f ? s3 : pw * s3;
                } else if (m == 1) {
                    v.x = fmaxf(s0, 0.f); v.y = fmaxf(s1, 0.f);
                    v.z = fmaxf(s2, 0.f); v.w = fmaxf(s3, 0.f);
                } else {
                    v.x = tanhf(s0); v.y = tanhf(s1);
                    v.z = tanhf(s2); v.w = tanhf(s3);
                }
                *(float4*)(op + rr * Wn) = v;
            }
        }
    } else {
        #pragma unroll
        for (int i = 0; i < 8; ++i) {
            const int co = co_base + co_off + i;
            const size_t off = ((size_t)b * Cn + co) * HW + (size_t)orow * Wn + ocol;
            #pragma unroll
            for (int rr = 0; rr < 2; ++rr) {
                const float4 xv = *(const float4*)(xres + off + rr * Wn);
                float4 v;
                v.x = fmaf(acc[i][rr * 4 + 0], 0.1f, xv.x);
                v.y = fmaf(acc[i][rr * 4 + 1], 0.1f, xv.y);
                v.z = fmaf(acc[i][rr * 4 + 2], 0.1f, xv.z);
                v.w = fmaf(acc[i][rr * 4 + 3], 0.1f, xv.w);
                *(float4*)(out + off + rr * Wn) = v;
            }
        }
    }
}

extern "C" void kernel_launch(void* const* d_in, const int* in_sizes, int n_in,
                              void* d_out, int out_size, void* d_ws, size_t ws_size,
                              hipStream_t stream) {
    const float* x  = (const float*)d_in[0];
    const float* w2 = (const float*)d_in[1];
    const float* w3 = (const float*)d_in[2];
    const float* pw = (const float*)d_in[3];
    // d_in[4..6] (idx_p/idx_r/idx_t) are the fixed 0/1/2 mod-3 arange patterns;
    // the permutation is hardcoded in the MODE-0 epilogue.
    float* out = (float*)d_out;
    float* ws  = (float*)d_ws;

    // Workspace layout (needs ~155.7 MB):
    //   wT2: Cn*Cn*9 floats, wT3: Cn*Cn*9 floats, a: B*C*H*W floats
    float* wT2 = ws;
    float* wT3 = ws + (size_t)Cn * Cn * 9;
    float* a   = ws + (size_t)2 * Cn * Cn * 9;

    const int nw = Cn * Cn * 9;
    transpose_w_k<<<(nw + 255) / 256, 256, 0, stream>>>(w2, wT2);
    transpose_w_k<<<(nw + 255) / 256, 256, 0, stream>>>(w3, wT3);

    dim3 grid(18, Cn / CO_T, Bn);   // (6 row-tiles * 3 col-tiles, 8 co-groups, 16 images)
    conv3x3_k<0><<<grid, 256, 0, stream>>>(x, wT2, pw, nullptr, a);
    conv3x3_k<1><<<grid, 256, 0, stream>>>(a, wT3, nullptr, x, out);
}

// Round 2
// 622.568 us; speedup vs baseline: 9.2782x; 9.2782x over previous
//
#include <hip/hip_runtime.h>
#include <math.h>

// ResBlock via bf16 MFMA implicit-GEMM conv3x3.
// B=16, C=256, H=W=96. Padded channels-last intermediates [16][98][98][256] bf16.

#define Bn 16
#define Cn 256
#define Hn 96
#define Wn 96
#define PH 98
#define PW 98
#define HW (Hn*Wn)

typedef __bf16 bf16x8 __attribute__((ext_vector_type(8)));
typedef float  f32x4  __attribute__((ext_vector_type(4)));

__device__ __forceinline__ unsigned short f2bf(float f) {
    unsigned int u = __float_as_uint(f);
    unsigned int r = (u + 0x7fffu + ((u >> 16) & 1u)) >> 16;
    return (unsigned short)r;
}

__device__ __forceinline__ void lds_load16(void* lds, const void* g) {
    auto gp = (const __attribute__((address_space(1))) char*)(unsigned long long)(uintptr_t)g;
    auto lp = (__attribute__((address_space(3))) char*)(unsigned int)(uintptr_t)lds;
    __builtin_amdgcn_global_load_lds(gp, lp, 16, 0, 0);
}

// ---- zero the padded border (h in {0,97} or w in {0,97}) of a CL tensor ----
__global__ __launch_bounds__(256)
void zero_border_k(unsigned short* __restrict__ t) {
    int idx = blockIdx.x * 256 + threadIdx.x;      // 16*388*32 = 198656 threads
    int oct = idx & 31;
    int rest = idx >> 5;
    int pidx = rest % 388;
    int b = rest / 388;
    int h, w;
    if (pidx < 98)       { h = 0;  w = pidx; }
    else if (pidx < 196) { h = 97; w = pidx - 98; }
    else if (pidx < 292) { h = pidx - 196 + 1; w = 0; }
    else                 { h = pidx - 292 + 1; w = 97; }
    size_t e = ((size_t)(b * PH + h) * PW + w) * 256 + oct * 8;
    *(uint4*)(t + e) = make_uint4(0u, 0u, 0u, 0u);
}

// ---- pack weights fp32 [co][ci][3][3] -> bf16 [cc][k9][c'][ci32] ----
// PERM: c' is the concat-order channel (conv1): src co = sigma(c').
template<bool PERM>
__global__ __launch_bounds__(256)
void pack_w_k(const float* __restrict__ w, unsigned short* __restrict__ wp) {
    int idx = blockIdx.x * 256 + threadIdx.x;      // 589824
    int ci_l = idx & 31;
    int c    = (idx >> 5) & 255;
    int v    = idx >> 13;          // 0..71
    int k9   = v % 9;
    int cc   = v / 9;
    int co;
    if (PERM) {
        co = (c < 86) ? c * 3 : (c < 171) ? (c - 86) * 3 + 1 : (c - 171) * 3 + 2;
    } else {
        co = c;
    }
    float val = w[((size_t)co * 256 + cc * 32 + ci_l) * 9 + k9];
    wp[idx] = f2bf(val);
}

// ---- x fp32 NCHW -> padded channels-last bf16 (interior only) ----
__global__ __launch_bounds__(256)
void transform_x_k(const float* __restrict__ x, unsigned short* __restrict__ xp) {
    __shared__ float s[32 * 33];
    const int t = threadIdx.x;
    const int col0 = blockIdx.x * 32;
    const int row  = blockIdx.y;
    const int z = blockIdx.z;
    const int b = z >> 3;
    const int ci0 = (z & 7) * 32;

    #pragma unroll
    for (int i = 0; i < 4; ++i) {
        int ci = i * 8 + (t >> 5);
        int px = t & 31;
        s[ci * 33 + px] = x[((size_t)(b * Cn + ci0 + ci)) * HW + row * Wn + col0 + px];
    }
    __syncthreads();
    const int px = t >> 3;
    const int c4 = (t & 7) * 4;
    ushort4 o;
    o.x = f2bf(s[(c4 + 0) * 33 + px]);
    o.y = f2bf(s[(c4 + 1) * 33 + px]);
    o.z = f2bf(s[(c4 + 2) * 33 + px]);
    o.w = f2bf(s[(c4 + 3) * 33 + px]);
    size_t e = ((size_t)(b * PH + row + 1) * PW + (col0 + px + 1)) * 256 + ci0 + c4;
    *(ushort4*)(xp + e) = o;
}

// ---- MFMA conv3x3: 64 co x (16x32 px) per block, 4 waves, K chunks of 32 ci ----
// MODE 0: in = x_pad, out = a_cl (activation, channels already in concat order)
// MODE 1: in = a_cl,  out = fp32 NCHW conv*0.1 + x
template<int MODE>
__global__ __launch_bounds__(256, 2)
void conv_k(const unsigned short* __restrict__ in_cl,
            const unsigned short* __restrict__ wp,
            const float* __restrict__ prelu_w,
            const float* __restrict__ xres,
            void* __restrict__ outp)
{
    __shared__ unsigned short s_x[640 * 32];     // [pixel(18x34 +pad)][ci32]
    __shared__ unsigned short s_w[9 * 64 * 32];  // [k9][co64][ci32]

    const int tid = threadIdx.x;
    // XCD-chunked swizzle: logical wg contiguous per XCD; co-group fastest.
    const int bid = blockIdx.x;
    const int wg = (bid & 7) * 144 + (bid >> 3);
    const int co_base = (wg & 3) * 64;
    const int t2 = wg >> 2;            // 0..287
    const int tile = t2 % 18;
    const int b = t2 / 18;
    const int R0 = (tile / 3) * 16;    // padded-row base of tile (= image row -1 +1)
    const int C0 = (tile % 3) * 32;

    const int lane = tid & 63;
    const int wv = tid >> 6;
    const int l15 = lane & 15;
    const int q = lane >> 4;

    const int xbase = 4 * wv * 1088 + l15 * 32 + q * 8;   // s_x ushort offset base
    const int wbase = l15 * 32 + q * 8;                   // s_w per-m base

    f32x4 acc[4][8];
    #pragma unroll
    for (int m = 0; m < 4; ++m)
        #pragma unroll
        for (int n = 0; n < 8; ++n) acc[m][n] = 0.f;

    const unsigned short* img = in_cl + (size_t)b * PH * PW * 256;

    for (int cc = 0; cc < 8; ++cc) {
        __syncthreads();
        // stage input tile: 18x34 pixels x 32 ci (+clamped pad to 640 px)
        #pragma unroll
        for (int i = 0; i < 10; ++i) {
            int idx = i * 256 + tid;
            int p = idx >> 2, qq = idx & 3;
            if (p > 611) p = 611;
            int pr = p / 34;
            int pc = p - pr * 34;
            const unsigned short* g = img + ((size_t)(R0 + pr) * PW + (C0 + pc)) * 256
                                          + cc * 32 + qq * 8;
            lds_load16(&s_x[(size_t)idx * 8], g);
        }
        // stage weights: 9 x 64co x 32ci
        #pragma unroll
        for (int k9 = 0; k9 < 9; ++k9) {
            const unsigned short* g = wp + ((size_t)(cc * 9 + k9) * 256 + co_base) * 32 + tid * 8;
            lds_load16(&s_w[k9 * 2048 + tid * 8], g);
        }
        __syncthreads();

        #pragma unroll
        for (int k9 = 0; k9 < 9; ++k9) {
            const int kh = k9 / 3;
            const int kw = k9 - 3 * kh;
            bf16x8 af[4];
            #pragma unroll
            for (int m = 0; m < 4; ++m)
                af[m] = *(const bf16x8*)&s_w[k9 * 2048 + m * 512 + wbase];
            #pragma unroll
            for (int n = 0; n < 8; ++n) {
                const bf16x8 bf = *(const bf16x8*)&s_x[xbase + ((n >> 1) + kh) * 1088
                                                       + ((n & 1) * 16 + kw) * 32];
                #pragma unroll
                for (int m = 0; m < 4; ++m)
                    acc[m][n] = __builtin_amdgcn_mfma_f32_16x16x32_bf16(af[m], bf, acc[m][n], 0, 0, 0);
            }
        }
    }

    if constexpr (MODE == 0) {
        const float pw = prelu_w[0];
        unsigned short* aout = (unsigned short*)outp;
        #pragma unroll
        for (int m = 0; m < 4; ++m) {
            const int cb = co_base + m * 16 + q * 4;
            #pragma unroll
            for (int n = 0; n < 8; ++n) {
                const int row_p = 4 * wv + (n >> 1);
                const int col_p = (n & 1) * 16 + l15;
                size_t pix = ((size_t)(b * PH + R0 + row_p + 1)) * PW + (C0 + col_p + 1);
                ushort4 o;
                float r[4];
                #pragma unroll
                for (int j = 0; j < 4; ++j) {
                    const int c = cb + j;
                    float s = acc[m][n][j];
                    if (c < 86)        r[j] = s >= 0.f ? s : pw * s;
                    else if (c < 171)  r[j] = fmaxf(s, 0.f);
                    else {
                        float e = __expf(2.f * s);
                        r[j] = 1.f - 2.f / (e + 1.f);
                    }
                }
                o.x = f2bf(r[0]); o.y = f2bf(r[1]); o.z = f2bf(r[2]); o.w = f2bf(r[3]);
                *(ushort4*)(aout + pix * 256 + cb) = o;
            }
        }
    } else {
        float* fout = (float*)outp;
        #pragma unroll
        for (int m = 0; m < 4; ++m) {
            const int cb = co_base + m * 16 + q * 4;
            #pragma unroll
            for (int n = 0; n < 8; ++n) {
                const int row_p = 4 * wv + (n >> 1);
                const int col_p = (n & 1) * 16 + l15;
                size_t base = ((size_t)(b * Cn + cb)) * HW + (size_t)(R0 + row_p) * Wn + (C0 + col_p);
                #pragma unroll
                for (int j = 0; j < 4; ++j)
                    fout[base + (size_t)j * HW] = acc[m][n][j] * 0.1f + xres[base + (size_t)j * HW];
            }
        }
    }
}

extern "C" void kernel_launch(void* const* d_in, const int* in_sizes, int n_in,
                              void* d_out, int out_size, void* d_ws, size_t ws_size,
                              hipStream_t stream) {
    const float* x  = (const float*)d_in[0];
    const float* w2 = (const float*)d_in[1];
    const float* w3 = (const float*)d_in[2];
    const float* pw = (const float*)d_in[3];
    float* out = (float*)d_out;
    char* ws = (char*)d_ws;

    // ws layout: a_cl (78,675,968 B) | wp2 (1,179,648 B) | wp3 (1,179,648 B)  = 81 MB
    unsigned short* a_cl = (unsigned short*)ws;
    unsigned short* wp2  = (unsigned short*)(ws + 78675968);
    unsigned short* wp3  = (unsigned short*)(ws + 78675968 + 1179648);
    // x_pad aliases d_out (78.7 MB <= 151 MB); dead before conv<1> writes d_out.
    unsigned short* x_pad = (unsigned short*)d_out;

    zero_border_k<<<776, 256, 0, stream>>>(x_pad);
    zero_border_k<<<776, 256, 0, stream>>>(a_cl);
    pack_w_k<true ><<<2304, 256, 0, stream>>>(w2, wp2);
    pack_w_k<false><<<2304, 256, 0, stream>>>(w3, wp3);
    transform_x_k<<<dim3(3, 96, 128), 256, 0, stream>>>(x, x_pad);

    conv_k<0><<<1152, 256, 0, stream>>>(x_pad, wp2, pw, nullptr, (void*)a_cl);
    conv_k<1><<<1152, 256, 0, stream>>>(a_cl, wp3, nullptr, x, (void*)out);
}